// Round 2
// baseline (1360.395 us; speedup 1.0000x reference)
//
#include <hip/hip_runtime.h>
#include <hip/hip_bf16.h>

// crossAttention on MI355X (gfx950).
// Convs as bf16 implicit-im2col GEMM from channels-last packed inputs.
// k-order: k = (kh*3+kw)*CI + ci  (matches reordered weights WB[co][p][ci]).

typedef unsigned short u16;
typedef short bf16x8 __attribute__((ext_vector_type(8)));
typedef float f32x4 __attribute__((ext_vector_type(4)));

__device__ __forceinline__ u16 f2bf(float f) {
  union { __hip_bfloat16 h; u16 u; } cv;
  cv.h = __float2bfloat16(f);
  return cv.u;
}

// ---------- weight cast+reorder: W[co][ci][3][3] f32 -> WB[co][p][ci] bf16 ----------
__global__ void wcast_kernel(const float* __restrict__ W, u16* __restrict__ WB, int CI) {
  const int co = blockIdx.x;
  const float* wr = W + (size_t)co * CI * 9;
  u16* wo = WB + (size_t)co * CI * 9;
  for (int ci = threadIdx.x; ci < CI; ci += blockDim.x) {
    #pragma unroll
    for (int p = 0; p < 9; ++p)
      wo[p * CI + ci] = f2bf(wr[(size_t)ci * 9 + p]);
  }
}

// ---------- pack NCHW f32 -> channels-last bf16 [b][h][w][ci] ----------
template<int CI, int HH>
__global__ void pack_cl_kernel(const float* __restrict__ x, u16* __restrict__ dst) {
  const int h = blockIdx.x, cg = blockIdx.y, b = blockIdx.z;  // cg: group of 256 ci
  __shared__ float tile[256][33];
  const int w = threadIdx.x & 31, crow = threadIdx.x >> 5;     // 8 c-rows per pass
  const float* xb = x + (size_t)b * CI * HH * HH;
  #pragma unroll 4
  for (int it = 0; it < 32; ++it) {
    int c = cg * 256 + it * 8 + crow;
    tile[it * 8 + crow][w] = xb[((size_t)c * HH + h) * HH + w];
  }
  __syncthreads();
  u16* db = dst + ((size_t)(b * HH + h) * HH) * CI + cg * 256 + threadIdx.x;
  #pragma unroll 4
  for (int w2 = 0; w2 < 32; ++w2)
    db[(size_t)w2 * CI] = f2bf(tile[threadIdx.x][w2]);
}

// ---------- bf16 MFMA GEMM with implicit im2col B ----------
// C[b][co][n] = sum_k A[co][k] * B[b][n][k] + bias[co]
// A: WB[co][9*CI] contiguous. B row n=(oh,ow): k=(p,ci) -> xcl[b][oh+kh][ow+kw][ci]
__device__ __forceinline__ void gload_lds16(const u16* g, u16* l) {
  __builtin_amdgcn_global_load_lds((const __attribute__((address_space(1))) void*)g,
                                   (__attribute__((address_space(3))) void*)l, 16, 0, 0);
}

template<int CI, int LOG2CI, int HH, int OHW>
__launch_bounds__(256, 2)
__global__ void conv_gemm_kernel(const u16* __restrict__ A0, const u16* __restrict__ A1, const u16* __restrict__ A2,
                                 const float* __restrict__ bb0, const float* __restrict__ bb1, const float* __restrict__ bb2,
                                 const u16* __restrict__ B0, const u16* __restrict__ B1, const u16* __restrict__ B2,
                                 float* __restrict__ C0, float* __restrict__ C1, float* __restrict__ C2) {
  constexpr int KTOT = 9 * CI;
  constexpr int NV = OHW * OHW;
  constexpr size_t BSTR = (size_t)HH * HH * CI;
  const int z = blockIdx.z, cvx = z >> 2, b = z & 3;
  const u16*   A    = cvx == 0 ? A0  : (cvx == 1 ? A1  : A2);
  const float* bias = cvx == 0 ? bb0 : (cvx == 1 ? bb1 : bb2);
  const u16*   Bm   = cvx == 0 ? B0  : (cvx == 1 ? B1  : B2);
  float*       C    = cvx == 0 ? C0  : (cvx == 1 ? C1  : C2);

  const int lane = threadIdx.x & 63;
  const int w    = threadIdx.x >> 6;   // wave 0..3 -> 2x2 over 128x128 tile
  const int wm = w >> 1, wn = w & 1;

  __shared__ u16 As[128 * 32];         // [row][32 k] (64B rows)
  __shared__ u16 Bs[128 * 32];

  // staging: wave covers rows c*16+l4, 16B chunk swz (source-side XOR swizzle)
  const int l4 = lane >> 2, lc = lane & 3;
  const int swz = lc ^ (l4 & 3);
  const int c0 = 2 * w, c1 = 2 * w + 1;

  const u16* ga0 = A + (size_t)(blockIdx.y * 128 + c0 * 16 + l4) * KTOT + swz * 8;
  const u16* ga1 = A + (size_t)(blockIdx.y * 128 + c1 * 16 + l4) * KTOT + swz * 8;

  const u16* Bb = Bm + (size_t)b * BSTR + swz * 8;
  int r0 = blockIdx.x * 128 + c0 * 16 + l4; if (r0 > NV - 1) r0 = NV - 1;
  int r1 = blockIdx.x * 128 + c1 * 16 + l4; if (r1 > NV - 1) r1 = NV - 1;
  const int oh0 = r0 / OHW, ow0 = r0 - oh0 * OHW;
  const int oh1 = r1 / OHW, ow1 = r1 - oh1 * OHW;
  const u16* rb0 = Bb + ((size_t)oh0 * HH + ow0) * CI;
  const u16* rb1 = Bb + ((size_t)oh1 * HH + ow1) * CI;

  // ds_read fragments: row (.. + fr), global k-chunk kg stored at slot kg^(row&3)
  const int fr = lane & 15, kg = lane >> 4;
  int aoff[4], boff[4];
  #pragma unroll
  for (int m = 0; m < 4; ++m) aoff[m] = (wm * 64 + m * 16 + fr) * 32 + ((kg ^ (fr & 3)) * 8);
  #pragma unroll
  for (int n = 0; n < 4; ++n) boff[n] = (wn * 64 + n * 16 + fr) * 32 + ((kg ^ (fr & 3)) * 8);

  f32x4 acc[4][4] = {};

  for (int kt = 0; kt < KTOT; kt += 32) {
    const int p   = kt >> LOG2CI;        // scalar: which (kh,kw)
    const int ci0 = kt & (CI - 1);
    const int kh = p / 3, kw = p - kh * 3;
    const int soff = (kh * HH + kw) * CI + ci0;
    gload_lds16(ga0, &As[c0 * 512]);
    gload_lds16(ga1, &As[c1 * 512]);
    gload_lds16(rb0 + soff, &Bs[c0 * 512]);
    gload_lds16(rb1 + soff, &Bs[c1 * 512]);
    ga0 += 32; ga1 += 32;
    __syncthreads();                     // drains vmcnt -> LDS valid
    bf16x8 af[4], bg[4];
    #pragma unroll
    for (int m = 0; m < 4; ++m) af[m] = *(const bf16x8*)&As[aoff[m]];
    #pragma unroll
    for (int n = 0; n < 4; ++n) bg[n] = *(const bf16x8*)&Bs[boff[n]];
    #pragma unroll
    for (int m = 0; m < 4; ++m)
      #pragma unroll
      for (int n = 0; n < 4; ++n)
        acc[m][n] = __builtin_amdgcn_mfma_f32_16x16x32_bf16(af[m], bg[n], acc[m][n], 0, 0, 0);
    __syncthreads();
  }

  // epilogue: C/D layout col=lane&15, row=(lane>>4)*4+j
  float* Cb = C + (size_t)b * 1024 * NV;
  #pragma unroll
  for (int m = 0; m < 4; ++m) {
    const int cobase = blockIdx.y * 128 + wm * 64 + m * 16 + kg * 4;
    #pragma unroll
    for (int j = 0; j < 4; ++j) {
      const int co = cobase + j;
      const float bv = bias[co];
      float* crow = Cb + (size_t)co * NV;
      #pragma unroll
      for (int n = 0; n < 4; ++n) {
        const int col = blockIdx.x * 128 + wn * 64 + n * 16 + fr;
        if (col < NV) crow[col] = acc[m][n][j] + bv;
      }
    }
  }
}

// ---------- QK: qk[b,c,h,g] = sum_w q[b,c,h,w]*k[b,c,g,w] / sqrt(2048) ----------
__global__ void qk_kernel(const float* __restrict__ q, const float* __restrict__ k,
                          float* __restrict__ qk) {
  const int bc = blockIdx.x;
  const float* qr = q + (size_t)bc * 900;
  const float* kr = k + (size_t)bc * 900;
  float* o = qk + (size_t)bc * 900;
  __shared__ float qs[900], ks[900];
  for (int i = threadIdx.x; i < 900; i += blockDim.x) { qs[i] = qr[i]; ks[i] = kr[i]; }
  __syncthreads();
  const float sc = 0.022097086912079608f;
  for (int i = threadIdx.x; i < 900; i += blockDim.x) {
    int h = i / 30, g = i - h * 30;
    float s = 0.f;
    #pragma unroll
    for (int ww = 0; ww < 30; ++ww) s += qs[h * 30 + ww] * ks[g * 30 + ww];
    o[i] = s * sc;
  }
}

// ---------- softmax over channel dim (axis c of [b][c][900]) ----------
__global__ void softmax_kernel(float* __restrict__ qk) {
  const int t = blockIdx.x, b = blockIdx.y;
  const int i = threadIdx.x & 127;
  const int half = threadIdx.x >> 7;
  const int p = t * 128 + i;
  const bool valid = p < 900;
  float* base = qk + (size_t)b * 1024 * 900 + p;
  float m = -1e30f, s = 0.f;
  if (valid) {
    for (int c = half; c < 1024; c += 2) {
      float v = base[(size_t)c * 900];
      if (v > m) { s = s * __expf(m - v) + 1.f; m = v; }
      else s += __expf(v - m);
    }
  }
  __shared__ float ms[2][128], ss[2][128];
  ms[half][i] = m; ss[half][i] = s;
  __syncthreads();
  const float M = fmaxf(ms[0][i], ms[1][i]);
  const float S = ss[0][i] * __expf(ms[0][i] - M) + ss[1][i] * __expf(ms[1][i] - M);
  const float inv = 1.f / S;
  if (valid) {
    for (int c = half; c < 1024; c += 2) {
      float v = base[(size_t)c * 900];
      base[(size_t)c * 900] = __expf(v - M) * inv;
    }
  }
}

// ---------- QKV: qkv[b,c,h,w] = sum_g s[b,c,h,g]*v[b,c,g,w] ----------
// CL=true: write bf16 channels-last [b][30][30][1024]; else f32 [b][c][900]
template<bool CL>
__global__ void qkv_kernel(const float* __restrict__ s, const float* __restrict__ v,
                           void* __restrict__ o) {
  const int bc = blockIdx.x, b = bc >> 10, c = bc & 1023;
  const float* sr = s + (size_t)bc * 900;
  const float* vr = v + (size_t)bc * 900;
  __shared__ float ssm[900], vsm[900];
  for (int i = threadIdx.x; i < 900; i += blockDim.x) { ssm[i] = sr[i]; vsm[i] = vr[i]; }
  __syncthreads();
  for (int i = threadIdx.x; i < 900; i += blockDim.x) {
    int h = i / 30, ww = i - h * 30;
    float acc = 0.f;
    #pragma unroll
    for (int g = 0; g < 30; ++g) acc += ssm[h * 30 + g] * vsm[g * 30 + ww];
    if (CL) ((u16*)o)[((size_t)(b * 30 + h) * 30 + ww) * 1024 + c] = f2bf(acc);
    else    ((float*)o)[(size_t)bc * 900 + i] = acc;
  }
}

// ---------- fallback: direct fp32 conv (small-ws emergency path) ----------
template<int CI, int HH, int OHW>
__global__ void conv_direct_kernel(const float* __restrict__ x, const float* __restrict__ W,
                                   const float* __restrict__ bias, float* __restrict__ out) {
  const int co = blockIdx.x, b = blockIdx.y;
  const float* xb = x + (size_t)b * CI * HH * HH;
  const float* wr = W + (size_t)co * CI * 9;
  constexpr int NPX = (OHW * OHW + 255) / 256;
  float acc[NPX];
  int ohv[NPX], owv[NPX];
  #pragma unroll
  for (int i = 0; i < NPX; ++i) {
    int n = threadIdx.x + i * 256;
    if (n >= OHW * OHW) n = 0;
    acc[i] = 0.f;
    ohv[i] = n / OHW; owv[i] = n - ohv[i] * OHW;
  }
  __shared__ float xs[HH * HH];
  for (int ci = 0; ci < CI; ++ci) {
    __syncthreads();
    for (int i = threadIdx.x; i < HH * HH; i += 256) xs[i] = xb[(size_t)ci * HH * HH + i];
    float w9[9];
    #pragma unroll
    for (int p = 0; p < 9; ++p) w9[p] = wr[(size_t)ci * 9 + p];
    __syncthreads();
    #pragma unroll
    for (int i = 0; i < NPX; ++i)
      #pragma unroll
      for (int kh = 0; kh < 3; ++kh)
        #pragma unroll
        for (int kw = 0; kw < 3; ++kw)
          acc[i] += xs[(ohv[i] + kh) * HH + owv[i] + kw] * w9[kh * 3 + kw];
  }
  const float bv = bias[co];
  #pragma unroll
  for (int i = 0; i < NPX; ++i) {
    int n = threadIdx.x + i * 256;
    if (n < OHW * OHW) out[((size_t)b * 1024 + co) * (OHW * OHW) + n] = acc[i] + bv;
  }
}

// ---------- workspace layouts ----------
static constexpr size_t SZ_WB1 = (size_t)1024 * 18432 * 2;  // 37,748,736
static constexpr size_t SZ_XBF = (size_t)4 * 32 * 32 * 2048 * 2;  // 33,554,432
static constexpr size_t SZ_ACT = (size_t)4 * 1024 * 900 * 4;      // 14,745,600
// fast: [WqB][WkB][WvB][xbf][ybf][q][k][v]; qk->WqB, qkvbf->WkB, WoB->WvB
static constexpr size_t F_WQB = 0, F_WKB = SZ_WB1, F_WVB = 2 * SZ_WB1;
static constexpr size_t F_XBF = 3 * SZ_WB1, F_YBF = F_XBF + SZ_XBF;
static constexpr size_t F_Q = F_YBF + SZ_XBF, F_K = F_Q + SZ_ACT, F_V = F_K + SZ_ACT;
static constexpr size_t F_END = F_V + SZ_ACT;               // 224,591,872
// mid: [WB][xbf][ybf][q][k][v]; qk->xbf, qkvbf->ybf, WoB->WB
static constexpr size_t M_WB = 0, M_XBF = SZ_WB1, M_YBF = M_XBF + SZ_XBF;
static constexpr size_t M_Q = M_YBF + SZ_XBF, M_K = M_Q + SZ_ACT, M_V = M_K + SZ_ACT;
static constexpr size_t M_END = M_V + SZ_ACT;               // 149,094,400
// fallback: [q][k][v][qk]; qkvf32->q
static constexpr size_t D_Q = 0, D_K = SZ_ACT, D_V = 2 * SZ_ACT, D_QK = 3 * SZ_ACT;

extern "C" void kernel_launch(void* const* d_in, const int* in_sizes, int n_in,
                              void* d_out, int out_size, void* d_ws, size_t ws_size,
                              hipStream_t stream) {
  (void)in_sizes; (void)n_in; (void)out_size;
  const float* x  = (const float*)d_in[0];
  const float* y  = (const float*)d_in[1];
  const float* Wq = (const float*)d_in[2];
  const float* bq = (const float*)d_in[3];
  const float* Wk = (const float*)d_in[4];
  const float* bk = (const float*)d_in[5];
  const float* Wv = (const float*)d_in[6];
  const float* bv = (const float*)d_in[7];
  const float* Wo = (const float*)d_in[8];
  const float* bo = (const float*)d_in[9];
  float* out = (float*)d_out;
  char* ws = (char*)d_ws;

  if (ws_size >= F_END) {
    // ---------------- fast path ----------------
    u16* wqB = (u16*)(ws + F_WQB); u16* wkB = (u16*)(ws + F_WKB); u16* wvB = (u16*)(ws + F_WVB);
    u16* xbf = (u16*)(ws + F_XBF); u16* ybf = (u16*)(ws + F_YBF);
    float* qb = (float*)(ws + F_Q); float* kb = (float*)(ws + F_K); float* vb = (float*)(ws + F_V);
    float* qkb = (float*)(ws + F_WQB);
    u16* qkvbf = (u16*)(ws + F_WKB);
    u16* woB = (u16*)(ws + F_WVB);

    wcast_kernel<<<1024, 256, 0, stream>>>(Wq, wqB, 2048);
    wcast_kernel<<<1024, 256, 0, stream>>>(Wk, wkB, 2048);
    wcast_kernel<<<1024, 256, 0, stream>>>(Wv, wvB, 2048);
    pack_cl_kernel<2048, 32><<<dim3(32, 8, 4), 256, 0, stream>>>(x, xbf);
    pack_cl_kernel<2048, 32><<<dim3(32, 8, 4), 256, 0, stream>>>(y, ybf);
    conv_gemm_kernel<2048, 11, 32, 30><<<dim3(8, 8, 12), 256, 0, stream>>>(
        wqB, wkB, wvB, bq, bk, bv, xbf, xbf, ybf, qb, kb, vb);
    wcast_kernel<<<1024, 256, 0, stream>>>(Wo, woB, 1024);
    qk_kernel<<<4096, 256, 0, stream>>>(qb, kb, qkb);
    softmax_kernel<<<dim3(8, 4), 256, 0, stream>>>(qkb);
    qkv_kernel<true><<<4096, 256, 0, stream>>>(qkb, vb, qkvbf);
    conv_gemm_kernel<1024, 10, 30, 28><<<dim3(7, 8, 4), 256, 0, stream>>>(
        woB, woB, woB, bo, bo, bo, qkvbf, qkvbf, qkvbf, out, out, out);
  } else if (ws_size >= M_END) {
    // ---------------- mid path (single reused weight buffer) ----------------
    u16* wB = (u16*)(ws + M_WB);
    u16* xbf = (u16*)(ws + M_XBF); u16* ybf = (u16*)(ws + M_YBF);
    float* qb = (float*)(ws + M_Q); float* kb = (float*)(ws + M_K); float* vb = (float*)(ws + M_V);
    float* qkb = (float*)(ws + M_XBF);
    u16* qkvbf = (u16*)(ws + M_YBF);

    pack_cl_kernel<2048, 32><<<dim3(32, 8, 4), 256, 0, stream>>>(x, xbf);
    pack_cl_kernel<2048, 32><<<dim3(32, 8, 4), 256, 0, stream>>>(y, ybf);
    wcast_kernel<<<1024, 256, 0, stream>>>(Wq, wB, 2048);
    conv_gemm_kernel<2048, 11, 32, 30><<<dim3(8, 8, 4), 256, 0, stream>>>(
        wB, wB, wB, bq, bq, bq, xbf, xbf, xbf, qb, qb, qb);
    wcast_kernel<<<1024, 256, 0, stream>>>(Wk, wB, 2048);
    conv_gemm_kernel<2048, 11, 32, 30><<<dim3(8, 8, 4), 256, 0, stream>>>(
        wB, wB, wB, bk, bk, bk, xbf, xbf, xbf, kb, kb, kb);
    wcast_kernel<<<1024, 256, 0, stream>>>(Wv, wB, 2048);
    conv_gemm_kernel<2048, 11, 32, 30><<<dim3(8, 8, 4), 256, 0, stream>>>(
        wB, wB, wB, bv, bv, bv, ybf, ybf, ybf, vb, vb, vb);
    qk_kernel<<<4096, 256, 0, stream>>>(qb, kb, qkb);
    softmax_kernel<<<dim3(8, 4), 256, 0, stream>>>(qkb);
    qkv_kernel<true><<<4096, 256, 0, stream>>>(qkb, vb, qkvbf);
    wcast_kernel<<<1024, 256, 0, stream>>>(Wo, wB, 1024);
    conv_gemm_kernel<1024, 10, 30, 28><<<dim3(7, 8, 4), 256, 0, stream>>>(
        wB, wB, wB, bo, bo, bo, qkvbf, qkvbf, qkvbf, out, out, out);
  } else {
    // ---------------- fallback: direct fp32 convs ----------------
    float* qb = (float*)(ws + D_Q); float* kb = (float*)(ws + D_K); float* vb = (float*)(ws + D_V);
    float* qkb = (float*)(ws + D_QK);
    float* qkvf = (float*)(ws + D_Q);  // overlay q (dead after qk_kernel)

    conv_direct_kernel<2048, 32, 30><<<dim3(1024, 4), 256, 0, stream>>>(x, Wq, bq, qb);
    conv_direct_kernel<2048, 32, 30><<<dim3(1024, 4), 256, 0, stream>>>(x, Wk, bk, kb);
    conv_direct_kernel<2048, 32, 30><<<dim3(1024, 4), 256, 0, stream>>>(y, Wv, bv, vb);
    qk_kernel<<<4096, 256, 0, stream>>>(qb, kb, qkb);
    softmax_kernel<<<dim3(8, 4), 256, 0, stream>>>(qkb);
    qkv_kernel<false><<<4096, 256, 0, stream>>>(qkb, vb, qkvf);
    conv_direct_kernel<1024, 30, 28><<<dim3(1024, 4), 256, 0, stream>>>(qkvf, Wo, bo, out);
  }
}